// Round 3
// baseline (639.160 us; speedup 1.0000x reference)
//
#include <hip/hip_runtime.h>
#include <hip/hip_bf16.h>

typedef __bf16 bf16x8 __attribute__((ext_vector_type(8)));
typedef float  f32x4  __attribute__((ext_vector_type(4)));

// LDS layout (bytes). Activations: 52 rows x 128 bf16, XOR-swizzled 16B k-blocks.
// mfma A-reads span rows 0..63 -> spill into the next region; spilled rows are
// masked garbage (output rows >= 50 never stored).
#define W_OFF 0            // weight K-half: 128n x 64k bf16, swizzled (16384 B)
#define A_OFF 16384        // act buf A: x1 then a1 (13312 B; read-span 16 KB)
#define X_OFF 29696        // act buf X: x, persists to pooling (13312 B)
// small area: double-buffered per-user state (parity p), then singles
#define S_IDX   43008      // 2 x 192 ints  (1536 B)
#define S_UATT  44544      // 2 x 128 f     (1024 B)
#define S_ULIN  45568      // 2 x 128 f     (1024 B)
#define S_LP0   46592      // 64 f
#define S_LP1   46848      // 64 f
#define S_ATT   47104      // 64 f
#define S_POOL  47360      // 128 f
#define S_COMB  47872      // 128 f
#define S_H1    48384      // 32 f
#define SMEM_TOTAL 48640   // -> 3 blocks/CU (160 KB / 48.6 KB)
#define WCHUNK 16384       // bf16 elems per full weight chunk in global
#define WHALF  8192        // bf16 elems per K-half

// ws layout (bytes): wprep(8 chunks) | Pi(bf16) | Pt | Pr | Pu | Pu2  (~36.6 MB)
#define WS_WPREP 0
#define WS_PI    262144
#define WS_PT    (WS_PI + 25600000)     // Pi: 100000*128 bf16
#define WS_PR    (WS_PT + 512000)       // Pt: 1000*128 fp32
#define WS_PU    (WS_PR + 3072)         // Pr: 6*128 fp32 (ne_b folded in)
#define WS_PU2   (WS_PU + 5120000)      // Pu: 10000*128 fp32

// ---------------- prep: fp32 [k][n] -> bf16 [chunk][khalf][n][swizzled k64] ----------
// chunks: 0-2 ne_w slices, 3 ne1_w, 4 att1_w[:128], 5 att2_w, 6 att1_w[128:], 7 lin_w[:128]
__global__ void prep_weights_kernel(const float* __restrict__ ne_w,
                                    const float* __restrict__ ne1_w,
                                    const float* __restrict__ att1_w,
                                    const float* __restrict__ att2_w,
                                    const float* __restrict__ lin_w,
                                    __hip_bfloat16* __restrict__ wout) {
  __shared__ float tile[64][65];
  const int bx = blockIdx.x;
  const int c = bx >> 2, kt = (bx >> 1) & 1, ntile = bx & 1;
  const float* src; int koff;
  if      (c < 3)  { src = ne_w;   koff = c * 128; }
  else if (c == 3) { src = ne1_w;  koff = 0; }
  else if (c == 4) { src = att1_w; koff = 0; }
  else if (c == 5) { src = att2_w; koff = 0; }
  else if (c == 6) { src = att1_w; koff = 128; }
  else             { src = lin_w;  koff = 0; }
  const int tx = threadIdx.x, ty = threadIdx.y;
#pragma unroll
  for (int r = 0; r < 16; ++r) {
    int k = kt * 64 + r * 4 + ty, n = ntile * 64 + tx;
    tile[r * 4 + ty][tx] = src[(koff + k) * 128 + n];   // coalesced over n
  }
  __syncthreads();
#pragma unroll
  for (int r = 0; r < 16; ++r) {
    int n = ntile * 64 + r * 4 + ty, k = kt * 64 + tx;  // chunk-local k in [0,128)
    int h = k >> 6, k64 = k & 63;
    int off = c * WCHUNK + h * WHALF + n * 64 + ((((k64 >> 3) ^ (n & 7))) << 3) + (k64 & 7);
    wout[off] = __float2bfloat16(tile[tx][r * 4 + ty]);
  }
}

// ---------------- helpers ----------------
__device__ __forceinline__ unsigned short bf_bits(float x) {
  return __builtin_bit_cast(unsigned short, __float2bfloat16(x));
}

// One K-half (64) of a 128-K GEMM. A from 16-blk-swizzled act buffer (full-K rows),
// B from 8-blk-swizzled LDS half-chunk. Wave tile 16m x 64n.
__device__ __forceinline__ void mfma_half(const __hip_bfloat16* sIn,
                                          const __hip_bfloat16* sWh,
                                          f32x4 acc[4], int h, int m16, int nh, int lane) {
  const int mr = lane & 15;
  const int kq = lane >> 4;            // 0..3
  const int arow = (m16 * 16 + mr) * 128;
#pragma unroll
  for (int ks = 0; ks < 2; ++ks) {
    const int kb16 = h * 8 + ks * 4 + kq;           // logical 16B-block in full K
    bf16x8 a = *(const bf16x8*)(sIn + arow + ((kb16 ^ mr) << 3));
    const int swzb = (((ks * 4 + kq) ^ (mr & 7)) << 3);
#pragma unroll
    for (int nt = 0; nt < 4; ++nt) {
      const int n = nh * 64 + nt * 16 + mr;         // n&7 == mr&7 -> swzb valid
      bf16x8 b = *(const bf16x8*)(sWh + n * 64 + swzb);
      acc[nt] = __builtin_amdgcn_mfma_f32_16x16x32_bf16(a, b, acc[nt], 0, 0, 0);
    }
  }
}

// bias + optional row-vector + relu + swizzled bf16 store (rows < 50 only)
__device__ __forceinline__ void epilogue(f32x4 acc[4], const float* __restrict__ bias,
                                         const float* addvec, __hip_bfloat16* sOut,
                                         int m16, int nh, int lane) {
  const int mr = lane & 15;
  const int rb = m16 * 16 + ((lane >> 4) << 2);
#pragma unroll
  for (int nt = 0; nt < 4; ++nt) {
    const int col = nh * 64 + nt * 16 + mr;
    float bv = bias[col];
    if (addvec) bv += addvec[col];
    const int cblk = col >> 3, clo = col & 7;
#pragma unroll
    for (int r = 0; r < 4; ++r) {
      const int row = rb + r;
      if (row < 50) {
        float v = fmaxf(acc[nt][r] + bv, 0.0f);
        sOut[row * 128 + ((cblk ^ (row & 15)) << 3) + clo] = __float2bfloat16(v);
      }
    }
  }
}

// ---------------- P-GEMM: P = table @ W_chunk (+opt bias), once per launch ----------
// (round-0 version: 1894 one-shot 64-row blocks — measured best)
// segs: Pi(i2e,c0,bf16 out) | Pt(t2e,c2) | Pr(r2e,c1,+ne_b) | Pu(u2e,c6) | Pu2(u2e,c7)
__global__ __launch_bounds__(512) void pgemm_kernel(
    const float* __restrict__ i2e, const float* __restrict__ r2e,
    const float* __restrict__ t2e, const float* __restrict__ u2e,
    const float* __restrict__ ne_b, const __hip_bfloat16* __restrict__ wprep,
    __hip_bfloat16* __restrict__ Pi, float* __restrict__ Pt, float* __restrict__ Pr,
    float* __restrict__ Pu, float* __restrict__ Pu2) {
  __shared__ __align__(16) __hip_bfloat16 sW[WCHUNK];
  __shared__ __align__(16) __hip_bfloat16 sA[64 * 128];
  const int tid = threadIdx.x, lane = tid & 63, wid = tid >> 6;
  const int m16 = wid & 3, nh = wid >> 2;
  const int bx = blockIdx.x;
  const float* src; const __hip_bfloat16* W; float* dst = nullptr;
  const float* addb = nullptr; bool bf_out = false;
  long rows0; int nrows;
  if (bx < 1563)      { src = i2e; W = wprep + 0 * WCHUNK; bf_out = true; rows0 = (long)bx * 64;          nrows = 100000; }
  else if (bx < 1579) { src = t2e; W = wprep + 2 * WCHUNK; dst = Pt;  rows0 = (long)(bx - 1563) * 64; nrows = 1000; }
  else if (bx < 1580) { src = r2e; W = wprep + 1 * WCHUNK; dst = Pr;  rows0 = 0;                      nrows = 6; addb = ne_b; }
  else if (bx < 1737) { src = u2e; W = wprep + 6 * WCHUNK; dst = Pu;  rows0 = (long)(bx - 1580) * 64; nrows = 10000; }
  else                { src = u2e; W = wprep + 7 * WCHUNK; dst = Pu2; rows0 = (long)(bx - 1737) * 64; nrows = 10000; }

#pragma unroll
  for (int i = 0; i < 4; ++i) {
    int g = tid + i * 512;
    __builtin_amdgcn_global_load_lds(
        (__attribute__((address_space(1))) void*)(void*)(W + g * 8),
        (__attribute__((address_space(3))) void*)(void*)(sW + g * 8), 16, 0, 0);
  }
  const float4* s4 = (const float4*)src;
#pragma unroll
  for (int i = 0; i < 2; ++i) {
    int g = tid + i * 512;   // 64 rows x 16 kb
    int row = g >> 4, kb = g & 15;
    float4 v0 = {0.f, 0.f, 0.f, 0.f}, v1 = {0.f, 0.f, 0.f, 0.f};
    if (rows0 + row < nrows) {
      long base = (rows0 + row) * 32 + kb * 2;
      v0 = s4[base]; v1 = s4[base + 1];
    }
    uint4 pk;
    pk.x = ((unsigned)bf_bits(v0.y) << 16) | bf_bits(v0.x);
    pk.y = ((unsigned)bf_bits(v0.w) << 16) | bf_bits(v0.z);
    pk.z = ((unsigned)bf_bits(v1.y) << 16) | bf_bits(v1.x);
    pk.w = ((unsigned)bf_bits(v1.w) << 16) | bf_bits(v1.z);
    *(uint4*)(sA + row * 128 + ((kb ^ (row & 15)) << 3)) = pk;
  }
  __syncthreads();

  f32x4 acc[4];
#pragma unroll
  for (int j = 0; j < 4; ++j) acc[j] = (f32x4){0.f, 0.f, 0.f, 0.f};
  mfma_half(sA, sW, acc, 0, m16, nh, lane);
  mfma_half(sA, sW + WHALF, acc, 1, m16, nh, lane);

  const int mr = lane & 15;
  const int rb = m16 * 16 + ((lane >> 4) << 2);
#pragma unroll
  for (int nt = 0; nt < 4; ++nt) {
    const int col = nh * 64 + nt * 16 + mr;
    const float bv = addb ? addb[col] : 0.f;
#pragma unroll
    for (int r = 0; r < 4; ++r) {
      const int row = rb + r;
      if (rows0 + row < nrows) {
        if (bf_out) Pi[(rows0 + row) * 128 + col] = __float2bfloat16(acc[nt][r]);
        else        dst[(rows0 + row) * 128 + col] = acc[nt][r] + bv;
      }
    }
  }
}

// ---------------- main fused kernel: persistent blocks, 1 block = ~5 users ---------
// grid = 768 = 256 CU x 3 blocks/CU. Per user, the tail (softmax..head) overlaps
// the next user's weight-chunk stage + idx/Pu prefetch (parity-flipped buffers).
__global__ __launch_bounds__(512, 6) void graphdec_main(
    const __hip_bfloat16* __restrict__ Pi, const float* __restrict__ Pt,
    const float* __restrict__ Pr, const float* __restrict__ Pu,
    const float* __restrict__ Pu2,
    const float* __restrict__ ne1_b, const float* __restrict__ att1_b,
    const float* __restrict__ att2_b, const float* __restrict__ att3_w,
    const float* __restrict__ lin_w, const float* __restrict__ lin_b,
    const float* __restrict__ w1_w, const float* __restrict__ w1_b,
    const float* __restrict__ bn1_g, const float* __restrict__ bn1_b,
    const float* __restrict__ bn1_m, const float* __restrict__ bn1_v,
    const float* __restrict__ w2_w, const float* __restrict__ w2_b,
    const float* __restrict__ bn2_g, const float* __restrict__ bn2_b,
    const float* __restrict__ bn2_m, const float* __restrict__ bn2_v,
    const float* __restrict__ w3_w, const float* __restrict__ w3_b,
    const int* __restrict__ user_idx, const int* __restrict__ item_idx,
    const int* __restrict__ rat_idx, const int* __restrict__ time_idx,
    const __hip_bfloat16* __restrict__ wprep, float* __restrict__ out) {
  __shared__ __align__(16) unsigned char smem[SMEM_TOTAL];
  __hip_bfloat16* sW = (__hip_bfloat16*)(smem + W_OFF);
  __hip_bfloat16* sA = (__hip_bfloat16*)(smem + A_OFF);
  __hip_bfloat16* sX = (__hip_bfloat16*)(smem + X_OFF);
  int*   sIdxB  = (int*)  (smem + S_IDX);    // 2 x 192
  float* sUattB = (float*)(smem + S_UATT);   // 2 x 128
  float* sUlinB = (float*)(smem + S_ULIN);   // 2 x 128
  float* sLP0   = (float*)(smem + S_LP0);
  float* sLP1   = (float*)(smem + S_LP1);
  float* sAtt   = (float*)(smem + S_ATT);
  float* sPooled= (float*)(smem + S_POOL);
  float* sComb  = (float*)(smem + S_COMB);
  float* sH1    = (float*)(smem + S_H1);
  // tail scratch over dead sA (last mfma read of sA ends before B12)
  float* sPool4 = (float*)(smem + A_OFF);          // 512 f
  float* sCombP = (float*)(smem + A_OFF + 2048);   // 512 f

  const int tid  = threadIdx.x;
  const int lane = tid & 63;
  const int wid  = tid >> 6;
  const int m16  = wid & 3;
  const int nh   = wid >> 2;

  // ---- per-lane att3 fragment (cols this lane owns in C-layout) ----
  float att3r[4];
#pragma unroll
  for (int nt = 0; nt < 4; ++nt) att3r[nt] = att3_w[nh * 64 + nt * 16 + (lane & 15)];

  auto stage16 = [&](const __hip_bfloat16* __restrict__ src) {
#pragma unroll
    for (int i = 0; i < 2; ++i) {
      int g = tid + i * 512;                // 1024 x 16B = 16 KB
      __builtin_amdgcn_global_load_lds(
          (__attribute__((address_space(1))) void*)(void*)(src + g * 8),
          (__attribute__((address_space(3))) void*)(void*)(sW + g * 8), 16, 0, 0);
    }
  };

  f32x4 acc[4];
  const f32x4 zf = {0.f, 0.f, 0.f, 0.f};
  auto zacc = [&]() {
#pragma unroll
    for (int j = 0; j < 4; ++j) acc[j] = zf;
  };

  // ---- prologue: first user's small state into parity 0; stage chunk3 h0 ----
  long u = blockIdx.x;
  {
    if (tid < 192) {
      int c = tid >> 6, l = tid & 63;
      int v = 0;
      if (l < 50) {
        const int* p = (c == 0) ? item_idx : (c == 1) ? rat_idx : time_idx;
        v = p[u * 50 + l];
      }
      sIdxB[tid] = v;
    }
    const int uid = user_idx[u];
    if (tid >= 256 && tid < 384)      sUattB[tid - 256] = Pu [(long)uid * 128 + (tid - 256)];
    else if (tid >= 384)              sUlinB[tid - 384] = Pu2[(long)uid * 128 + (tid - 384)];
    stage16(wprep + 3 * WCHUNK);
  }

  for (int it = 0; u < 4096; u += gridDim.x, ++it) {
    const int p = it & 1;
    const int*   sIdx  = sIdxB  + p * 192;
    const float* sUatt = sUattB + p * 128;
    const float* sUlin = sUlinB + p * 128;
    __syncthreads();  // B0: sIdx/sUatt/sUlin[p] + sW(chunk3 h0) visible

    // ===== phase 0: x1 = relu(Pi[item]+Pr'[rat]+Pt[time]) -> sA =====
#pragma unroll
    for (int i = 0; i < 2; ++i) {
      int g = tid + i * 512;
      if (g < 832) {                         // 52 rows x 16 kb-blocks of 8 elems
        int row = g >> 4, kb = g & 15;
        uint4 pk = {0u, 0u, 0u, 0u};
        if (row < 50) {
          const bf16x8 pv = *(const bf16x8*)(Pi + (long)sIdx[row] * 128 + kb * 8);
          const float4* pr4 = (const float4*)(Pr + (long)sIdx[64 + row] * 128) + kb * 2;
          const float4* pt4 = (const float4*)(Pt + (long)sIdx[128 + row] * 128) + kb * 2;
          float4 r0 = pr4[0], r1 = pr4[1];
          float4 t0 = pt4[0], t1 = pt4[1];
          float s0 = fmaxf((float)pv[0] + r0.x + t0.x, 0.f);
          float s1 = fmaxf((float)pv[1] + r0.y + t0.y, 0.f);
          float s2 = fmaxf((float)pv[2] + r0.z + t0.z, 0.f);
          float s3 = fmaxf((float)pv[3] + r0.w + t0.w, 0.f);
          float s4 = fmaxf((float)pv[4] + r1.x + t1.x, 0.f);
          float s5 = fmaxf((float)pv[5] + r1.y + t1.y, 0.f);
          float s6 = fmaxf((float)pv[6] + r1.z + t1.z, 0.f);
          float s7 = fmaxf((float)pv[7] + r1.w + t1.w, 0.f);
          pk.x = ((unsigned)bf_bits(s1) << 16) | bf_bits(s0);
          pk.y = ((unsigned)bf_bits(s3) << 16) | bf_bits(s2);
          pk.z = ((unsigned)bf_bits(s5) << 16) | bf_bits(s4);
          pk.w = ((unsigned)bf_bits(s7) << 16) | bf_bits(s6);
        }
        *(uint4*)(sA + row * 128 + ((kb ^ (row & 15)) << 3)) = pk;
      }
    }
    __syncthreads();  // B1

    // ===== ne1: x = relu(x1 @ ne1_w + b) =====
    zacc();
    mfma_half(sA, sW, acc, 0, m16, nh, lane);
    __syncthreads();  // B2
    stage16(wprep + 3 * WCHUNK + WHALF);
    __syncthreads();  // B3
    mfma_half(sA, sW, acc, 1, m16, nh, lane);
    __syncthreads();  // B4
    stage16(wprep + 4 * WCHUNK);
    epilogue(acc, ne1_b, nullptr, sX, m16, nh, lane);  // x -> sX
    __syncthreads();  // B5

    // ===== att1: a1 = relu(x @ att1_w[:128] + Pu[u] + b) =====
    zacc();
    mfma_half(sX, sW, acc, 0, m16, nh, lane);
    __syncthreads();  // B6
    stage16(wprep + 4 * WCHUNK + WHALF);
    __syncthreads();  // B7
    mfma_half(sX, sW, acc, 1, m16, nh, lane);
    __syncthreads();  // B8
    stage16(wprep + 5 * WCHUNK);
    epilogue(acc, att1_b, sUatt, sA, m16, nh, lane);   // a1 -> sA
    __syncthreads();  // B9

    // ===== att2 + in-register logits =====
    zacc();
    mfma_half(sA, sW, acc, 0, m16, nh, lane);
    __syncthreads();  // B10
    stage16(wprep + 5 * WCHUNK + WHALF);
    __syncthreads();  // B11
    mfma_half(sA, sW, acc, 1, m16, nh, lane);
    {
      float lp[4] = {0.f, 0.f, 0.f, 0.f};
#pragma unroll
      for (int nt = 0; nt < 4; ++nt) {
        const int col = nh * 64 + nt * 16 + (lane & 15);
        const float b2 = att2_b[col];
#pragma unroll
        for (int r = 0; r < 4; ++r)
          lp[r] += fmaxf(acc[nt][r] + b2, 0.f) * att3r[nt];
      }
#pragma unroll
      for (int off = 1; off < 16; off <<= 1) {
#pragma unroll
        for (int r = 0; r < 4; ++r) lp[r] += __shfl_xor(lp[r], off);
      }
      if ((lane & 15) == 0) {
        const int rowb = m16 * 16 + ((lane >> 4) << 2);
        float* dst = nh ? sLP1 : sLP0;
#pragma unroll
        for (int r = 0; r < 4; ++r) dst[rowb + r] = lp[r];
      }
    }
    __syncthreads();  // B12  (sW and sA both dead from here to next B0/B1)

    // ---- tail-overlap prefetch for next user ----
    const long nu = u + gridDim.x;
    const bool more = nu < 4096;
    if (more) stage16(wprep + 3 * WCHUNK);   // next user's chunk3 h0 into dead sW
    int pv = 0; float puv = 0.f, pu2v = 0.f;
    if (more) {
      if (tid < 192) {
        int c = tid >> 6, l = tid & 63;
        if (l < 50) {
          const int* pp = (c == 0) ? item_idx : (c == 1) ? rat_idx : time_idx;
          pv = pp[nu * 50 + l];
        }
      }
      const int nuid = user_idx[nu];
      if (tid >= 256 && tid < 384)      puv  = Pu [(long)nuid * 128 + (tid - 256)];
      else if (tid >= 384)              pu2v = Pu2[(long)nuid * 128 + (tid - 384)];
    }

    // ===== softmax over 50 (wave 0; att3_b cancels under softmax) =====
    if (wid == 0) {
      float v = (lane < 50) ? (sLP0[lane] + sLP1[lane]) : -3.4e38f;
      float m = v;
      for (int off = 32; off > 0; off >>= 1) m = fmaxf(m, __shfl_xor(m, off));
      float e = (lane < 50) ? __expf(v - m) : 0.f;
      float s = e;
      for (int off = 32; off > 0; off >>= 1) s += __shfl_xor(s, off);
      sAtt[lane] = e / s;
    }
    __syncthreads();  // B13

    // ===== pooled partials (4 per d), scratch over dead sA =====
    {
      int q = tid >> 7, d = tid & 127;
      const int cblk = d >> 3, clo = d & 7;
      float s = 0.f;
      for (int l = q; l < 50; l += 4)
        s += sAtt[l] * (float)sX[l * 128 + ((cblk ^ (l & 15)) << 3) + clo];
      sPool4[q * 128 + d] = s;
    }
    __syncthreads();  // B14
    if (tid < 128)
      sPooled[tid] = sPool4[tid] + sPool4[128 + tid] + sPool4[256 + tid] + sPool4[384 + tid];
    __syncthreads();  // B15

    // ===== comb = relu(Pu2[u] + pooled @ lin_w[128:] + lin_b), 4 k-partials =====
    {
      int q = tid >> 7, d = tid & 127;
      float s = 0.f;
      for (int j = q * 32; j < q * 32 + 32; ++j) s += sPooled[j] * lin_w[(128 + j) * 128 + d];
      sCombP[q * 128 + d] = s;
    }
    __syncthreads();  // B16

    // write prefetched small state to parity p^1 (loads landed long ago)
    if (more) {
      int*   nIdx  = sIdxB  + (p ^ 1) * 192;
      float* nUatt = sUattB + (p ^ 1) * 128;
      float* nUlin = sUlinB + (p ^ 1) * 128;
      if (tid < 192) nIdx[tid] = pv;
      if (tid >= 256 && tid < 384)      nUatt[tid - 256] = puv;
      else if (tid >= 384)              nUlin[tid - 384] = pu2v;
    }
    if (tid < 128)
      sComb[tid] = fmaxf(sCombP[tid] + sCombP[128 + tid] + sCombP[256 + tid] + sCombP[384 + tid]
                         + sUlin[tid] + lin_b[tid], 0.f);
    __syncthreads();  // B17

    // ===== head entirely in wave 0 =====
    if (wid == 0) {
      if (lane < 32) {
        float s = w1_b[lane];
        for (int k = 0; k < 128; ++k) s += sComb[k] * w1_w[k * 32 + lane];
        s = (s - bn1_m[lane]) * rsqrtf(bn1_v[lane] + 1e-5f) * bn1_g[lane] + bn1_b[lane];
        sH1[lane] = fmaxf(s, 0.f);
      }
      if (lane < 16) {
        float s = w2_b[lane];
        for (int k = 0; k < 32; ++k) s += sH1[k] * w2_w[k * 16 + lane];
        s = (s - bn2_m[lane]) * rsqrtf(bn2_v[lane] + 1e-5f) * bn2_g[lane] + bn2_b[lane];
        float q = fmaxf(s, 0.f) * w3_w[lane];   // relu(h2) then dot w3
        q += __shfl_xor(q, 1); q += __shfl_xor(q, 2);
        q += __shfl_xor(q, 4); q += __shfl_xor(q, 8);
        if (lane == 0) out[u] = q + w3_b[0];
      }
    }
    // loop-top B0 separates head reads (sComb/sH1) and scratch from next user's writes
  }
}

extern "C" void kernel_launch(void* const* d_in, const int* in_sizes, int n_in,
                              void* d_out, int out_size, void* d_ws, size_t ws_size,
                              hipStream_t stream) {
  const float* u2e    = (const float*)d_in[0];
  const float* i2e    = (const float*)d_in[1];
  const float* r2e    = (const float*)d_in[2];
  const float* t2e    = (const float*)d_in[3];
  const float* ne_w   = (const float*)d_in[4];
  const float* ne_b   = (const float*)d_in[5];
  const float* ne1_w  = (const float*)d_in[6];
  const float* ne1_b  = (const float*)d_in[7];
  const float* att1_w = (const float*)d_in[8];
  const float* att1_b = (const float*)d_in[9];
  const float* att2_w = (const float*)d_in[10];
  const float* att2_b = (const float*)d_in[11];
  const float* att3_w = (const float*)d_in[12];
  const float* att3_b = (const float*)d_in[13];
  const float* lin_w  = (const float*)d_in[14];
  const float* lin_b  = (const float*)d_in[15];
  const float* w1_w   = (const float*)d_in[16];
  const float* w1_b   = (const float*)d_in[17];
  const float* bn1_g  = (const float*)d_in[18];
  const float* bn1_b  = (const float*)d_in[19];
  const float* bn1_m  = (const float*)d_in[20];
  const float* bn1_v  = (const float*)d_in[21];
  const float* w2_w   = (const float*)d_in[22];
  const float* w2_b   = (const float*)d_in[23];
  const float* bn2_g  = (const float*)d_in[24];
  const float* bn2_b  = (const float*)d_in[25];
  const float* bn2_m  = (const float*)d_in[26];
  const float* bn2_v  = (const float*)d_in[27];
  const float* w3_w   = (const float*)d_in[28];
  const float* w3_b   = (const float*)d_in[29];
  const int* user_idx = (const int*)d_in[30];
  const int* item_idx = (const int*)d_in[31];
  const int* rat_idx  = (const int*)d_in[32];
  const int* time_idx = (const int*)d_in[33];
  (void)att3_b;  // constant shift under softmax — cancels

  char* ws = (char*)d_ws;
  __hip_bfloat16* wprep = (__hip_bfloat16*)(ws + WS_WPREP);
  __hip_bfloat16* Pi = (__hip_bfloat16*)(ws + WS_PI);
  float* Pt  = (float*)(ws + WS_PT);
  float* Pr  = (float*)(ws + WS_PR);
  float* Pu  = (float*)(ws + WS_PU);
  float* Pu2 = (float*)(ws + WS_PU2);
  float* out = (float*)d_out;

  prep_weights_kernel<<<32, dim3(64, 4), 0, stream>>>(ne_w, ne1_w, att1_w, att2_w,
                                                      lin_w, wprep);
  pgemm_kernel<<<1894, 512, 0, stream>>>(i2e, r2e, t2e, u2e, ne_b, wprep,
                                         Pi, Pt, Pr, Pu, Pu2);
  graphdec_main<<<768, 512, 0, stream>>>(
      Pi, Pt, Pr, Pu, Pu2, ne1_b, att1_b, att2_b, att3_w,
      lin_w, lin_b, w1_w, w1_b, bn1_g, bn1_b, bn1_m, bn1_v, w2_w, w2_b,
      bn2_g, bn2_b, bn2_m, bn2_v, w3_w, w3_b,
      user_idx, item_idx, rat_idx, time_idx, wprep, out);
}

// Round 5
// 249.267 us; speedup vs baseline: 2.5642x; 2.5642x over previous
//
#include <hip/hip_runtime.h>
#include <hip/hip_bf16.h>

typedef __bf16 bf16x8 __attribute__((ext_vector_type(8)));
typedef float  f32x4  __attribute__((ext_vector_type(4)));

// ---- main-kernel LDS layout (bytes). 2 users per 512-thread block, 4 waves each. --
// Activations: 52 rows x 128 bf16 per user, XOR-swizzled 16B k-blocks.
// mfma A-reads span rows 0..63 -> spill into the following region; spilled rows are
// masked garbage (output rows >= 50 never stored). All regions they spill into are
// stable during the mfma phases (lockstep barrier schedule).
#define W_OFF 0            // shared weight K-half: 128n x 64k bf16, swizzled (16384 B)
#define A_OFF 16384        // act buf A per user (13312 B each; user stride 13312)
#define X_OFF 43008        // act buf X per user (13312 B each)
#define SMALL 69632        // small persistent arrays, 4096 B per user
#define SMEM_TOTAL 77824   // -> 2 blocks/CU (160 KB / 76 KB), 16 waves/CU
#define WCHUNK 16384       // bf16 elems per full weight chunk in global
#define WHALF  8192        // bf16 elems per K-half

// ws layout (bytes): wprep(8 chunks) | Pi(bf16) | Pt | Pr | Pu | Pu2  (~36.6 MB)
#define WS_WPREP 0
#define WS_PI    262144
#define WS_PT    (WS_PI + 25600000)     // Pi: 100000*128 bf16
#define WS_PR    (WS_PT + 512000)       // Pt: 1000*128 fp32
#define WS_PU    (WS_PR + 3072)        // Pr: 6*128 fp32 (ne_b folded in)
#define WS_PU2   (WS_PU + 5120000)      // Pu: 10000*128 fp32

// ---------------- prep: fp32 [k][n] -> bf16 [chunk][khalf][n][swizzled k64] ----------
// chunks: 0-2 ne_w slices, 3 ne1_w, 4 att1_w[:128], 5 att2_w, 6 att1_w[128:], 7 lin_w[:128]
__global__ void prep_weights_kernel(const float* __restrict__ ne_w,
                                    const float* __restrict__ ne1_w,
                                    const float* __restrict__ att1_w,
                                    const float* __restrict__ att2_w,
                                    const float* __restrict__ lin_w,
                                    __hip_bfloat16* __restrict__ wout) {
  __shared__ float tile[64][65];
  const int bx = blockIdx.x;
  const int c = bx >> 2, kt = (bx >> 1) & 1, ntile = bx & 1;
  const float* src; int koff;
  if      (c < 3)  { src = ne_w;   koff = c * 128; }
  else if (c == 3) { src = ne1_w;  koff = 0; }
  else if (c == 4) { src = att1_w; koff = 0; }
  else if (c == 5) { src = att2_w; koff = 0; }
  else if (c == 6) { src = att1_w; koff = 128; }
  else             { src = lin_w;  koff = 0; }
  const int tx = threadIdx.x, ty = threadIdx.y;
#pragma unroll
  for (int r = 0; r < 16; ++r) {
    int k = kt * 64 + r * 4 + ty, n = ntile * 64 + tx;
    tile[r * 4 + ty][tx] = src[(koff + k) * 128 + n];   // coalesced over n
  }
  __syncthreads();
#pragma unroll
  for (int r = 0; r < 16; ++r) {
    int n = ntile * 64 + r * 4 + ty, k = kt * 64 + tx;  // chunk-local k in [0,128)
    int h = k >> 6, k64 = k & 63;
    int off = c * WCHUNK + h * WHALF + n * 64 + ((((k64 >> 3) ^ (n & 7))) << 3) + (k64 & 7);
    wout[off] = __float2bfloat16(tile[tx][r * 4 + ty]);
  }
}

// ---------------- helpers ----------------
__device__ __forceinline__ unsigned short bf_bits(float x) {
  return __builtin_bit_cast(unsigned short, __float2bfloat16(x));
}

// One K-half (64) of a 128-K GEMM, full 128-col wave tile (16m x 128n).
// A from 16-blk-swizzled act buffer (full-K rows), B from 8-blk-swizzled LDS half-chunk.
__device__ __forceinline__ void mfma_half8(const __hip_bfloat16* sIn,
                                           const __hip_bfloat16* sWh,
                                           f32x4 acc[8], int h, int m16, int lane) {
  const int mr = lane & 15;
  const int kq = lane >> 4;            // 0..3
  const int arow = (m16 * 16 + mr) * 128;
#pragma unroll
  for (int ks = 0; ks < 2; ++ks) {
    const int kb16 = h * 8 + ks * 4 + kq;           // logical 16B-block in full K
    bf16x8 a = *(const bf16x8*)(sIn + arow + ((kb16 ^ mr) << 3));
    const int swzb = (((ks * 4 + kq) ^ (mr & 7)) << 3);
#pragma unroll
    for (int nt = 0; nt < 8; ++nt) {
      const int n = nt * 16 + mr;                   // n&7 == mr&7 -> swzb valid
      bf16x8 b = *(const bf16x8*)(sWh + n * 64 + swzb);
      acc[nt] = __builtin_amdgcn_mfma_f32_16x16x32_bf16(a, b, acc[nt], 0, 0, 0);
    }
  }
}

// bias + optional row-vector + relu + swizzled bf16 store (rows < 50 only)
__device__ __forceinline__ void epilogue8(f32x4 acc[8], const float* __restrict__ bias,
                                          const float* addvec, __hip_bfloat16* sOut,
                                          int m16, int lane) {
  const int mr = lane & 15;
  const int rb = m16 * 16 + ((lane >> 4) << 2);
#pragma unroll
  for (int nt = 0; nt < 8; ++nt) {
    const int col = nt * 16 + mr;
    float bv = bias[col];
    if (addvec) bv += addvec[col];
    const int cblk = col >> 3, clo = col & 7;
#pragma unroll
    for (int r = 0; r < 4; ++r) {
      const int row = rb + r;
      if (row < 50) {
        float v = fmaxf(acc[nt][r] + bv, 0.0f);
        sOut[row * 128 + ((cblk ^ (row & 15)) << 3) + clo] = __float2bfloat16(v);
      }
    }
  }
}

// legacy 64-col tile version for pgemm (wave tile 16m x 64n)
__device__ __forceinline__ void mfma_half(const __hip_bfloat16* sIn,
                                          const __hip_bfloat16* sWh,
                                          f32x4 acc[4], int h, int m16, int nh, int lane) {
  const int mr = lane & 15;
  const int kq = lane >> 4;
  const int arow = (m16 * 16 + mr) * 128;
#pragma unroll
  for (int ks = 0; ks < 2; ++ks) {
    const int kb16 = h * 8 + ks * 4 + kq;
    bf16x8 a = *(const bf16x8*)(sIn + arow + ((kb16 ^ mr) << 3));
    const int swzb = (((ks * 4 + kq) ^ (mr & 7)) << 3);
#pragma unroll
    for (int nt = 0; nt < 4; ++nt) {
      const int n = nh * 64 + nt * 16 + mr;
      bf16x8 b = *(const bf16x8*)(sWh + n * 64 + swzb);
      acc[nt] = __builtin_amdgcn_mfma_f32_16x16x32_bf16(a, b, acc[nt], 0, 0, 0);
    }
  }
}

// ---------------- P-GEMM: P = table @ W_chunk (+opt bias), once per launch ----------
// (round-0 version: 1894 one-shot 64-row blocks — measured best)
// segs: Pi(i2e,c0,bf16 out) | Pt(t2e,c2) | Pr(r2e,c1,+ne_b) | Pu(u2e,c6) | Pu2(u2e,c7)
__global__ __launch_bounds__(512) void pgemm_kernel(
    const float* __restrict__ i2e, const float* __restrict__ r2e,
    const float* __restrict__ t2e, const float* __restrict__ u2e,
    const float* __restrict__ ne_b, const __hip_bfloat16* __restrict__ wprep,
    __hip_bfloat16* __restrict__ Pi, float* __restrict__ Pt, float* __restrict__ Pr,
    float* __restrict__ Pu, float* __restrict__ Pu2) {
  __shared__ __align__(16) __hip_bfloat16 sW[WCHUNK];
  __shared__ __align__(16) __hip_bfloat16 sA[64 * 128];
  const int tid = threadIdx.x, lane = tid & 63, wid = tid >> 6;
  const int m16 = wid & 3, nh = wid >> 2;
  const int bx = blockIdx.x;
  const float* src; const __hip_bfloat16* W; float* dst = nullptr;
  const float* addb = nullptr; bool bf_out = false;
  long rows0; int nrows;
  if (bx < 1563)      { src = i2e; W = wprep + 0 * WCHUNK; bf_out = true; rows0 = (long)bx * 64;          nrows = 100000; }
  else if (bx < 1579) { src = t2e; W = wprep + 2 * WCHUNK; dst = Pt;  rows0 = (long)(bx - 1563) * 64; nrows = 1000; }
  else if (bx < 1580) { src = r2e; W = wprep + 1 * WCHUNK; dst = Pr;  rows0 = 0;                      nrows = 6; addb = ne_b; }
  else if (bx < 1737) { src = u2e; W = wprep + 6 * WCHUNK; dst = Pu;  rows0 = (long)(bx - 1580) * 64; nrows = 10000; }
  else                { src = u2e; W = wprep + 7 * WCHUNK; dst = Pu2; rows0 = (long)(bx - 1737) * 64; nrows = 10000; }

#pragma unroll
  for (int i = 0; i < 4; ++i) {
    int g = tid + i * 512;
    __builtin_amdgcn_global_load_lds(
        (__attribute__((address_space(1))) void*)(void*)(W + g * 8),
        (__attribute__((address_space(3))) void*)(void*)(sW + g * 8), 16, 0, 0);
  }
  const float4* s4 = (const float4*)src;
#pragma unroll
  for (int i = 0; i < 2; ++i) {
    int g = tid + i * 512;   // 64 rows x 16 kb
    int row = g >> 4, kb = g & 15;
    float4 v0 = {0.f, 0.f, 0.f, 0.f}, v1 = {0.f, 0.f, 0.f, 0.f};
    if (rows0 + row < nrows) {
      long base = (rows0 + row) * 32 + kb * 2;
      v0 = s4[base]; v1 = s4[base + 1];
    }
    uint4 pk;
    pk.x = ((unsigned)bf_bits(v0.y) << 16) | bf_bits(v0.x);
    pk.y = ((unsigned)bf_bits(v0.w) << 16) | bf_bits(v0.z);
    pk.z = ((unsigned)bf_bits(v1.y) << 16) | bf_bits(v1.x);
    pk.w = ((unsigned)bf_bits(v1.w) << 16) | bf_bits(v1.z);
    *(uint4*)(sA + row * 128 + ((kb ^ (row & 15)) << 3)) = pk;
  }
  __syncthreads();

  f32x4 acc[4];
#pragma unroll
  for (int j = 0; j < 4; ++j) acc[j] = (f32x4){0.f, 0.f, 0.f, 0.f};
  mfma_half(sA, sW, acc, 0, m16, nh, lane);
  mfma_half(sA, sW + WHALF, acc, 1, m16, nh, lane);

  const int mr = lane & 15;
  const int rb = m16 * 16 + ((lane >> 4) << 2);
#pragma unroll
  for (int nt = 0; nt < 4; ++nt) {
    const int col = nh * 64 + nt * 16 + mr;
    const float bv = addb ? addb[col] : 0.f;
#pragma unroll
    for (int r = 0; r < 4; ++r) {
      const int row = rb + r;
      if (rows0 + row < nrows) {
        if (bf_out) Pi[(rows0 + row) * 128 + col] = __float2bfloat16(acc[nt][r]);
        else        dst[(rows0 + row) * 128 + col] = acc[nt][r] + bv;
      }
    }
  }
}

// ---------------- main fused kernel: 1 block = 2 users (4 waves each) -------------
// Same 18-barrier straight-line schedule as the 98-µs version, but each weight stage
// and barrier now serves 2 users. 2 blocks/CU -> 4 users in flight per CU (vs 3).
__global__ __launch_bounds__(512, 4) void graphdec_main(
    const __hip_bfloat16* __restrict__ Pi, const float* __restrict__ Pt,
    const float* __restrict__ Pr, const float* __restrict__ Pu,
    const float* __restrict__ Pu2,
    const float* __restrict__ ne1_b, const float* __restrict__ att1_b,
    const float* __restrict__ att2_b, const float* __restrict__ att3_w,
    const float* __restrict__ lin_w, const float* __restrict__ lin_b,
    const float* __restrict__ w1_w, const float* __restrict__ w1_b,
    const float* __restrict__ bn1_g, const float* __restrict__ bn1_b,
    const float* __restrict__ bn1_m, const float* __restrict__ bn1_v,
    const float* __restrict__ w2_w, const float* __restrict__ w2_b,
    const float* __restrict__ bn2_g, const float* __restrict__ bn2_b,
    const float* __restrict__ bn2_m, const float* __restrict__ bn2_v,
    const float* __restrict__ w3_w, const float* __restrict__ w3_b,
    const int* __restrict__ user_idx, const int* __restrict__ item_idx,
    const int* __restrict__ rat_idx, const int* __restrict__ time_idx,
    const __hip_bfloat16* __restrict__ wprep, float* __restrict__ out) {
  __shared__ __align__(16) unsigned char smem[SMEM_TOTAL];
  __hip_bfloat16* sW = (__hip_bfloat16*)(smem + W_OFF);

  const int tid  = threadIdx.x;
  const int lane = tid & 63;
  const int wid  = tid >> 6;         // 0..7
  const int uw   = wid >> 2;         // user slot of this wave (0/1)
  const int m16  = wid & 3;          // 16-row tile within user
  const int ut   = tid >> 8;         // user slot of this thread (t256 groups)
  const int t256 = tid & 255;        // per-user thread id
  const long b   = blockIdx.x;

  // per-user region pointers (wave view and t256 view)
  __hip_bfloat16* sAw = (__hip_bfloat16*)(smem + A_OFF + uw * 13312);
  __hip_bfloat16* sXw = (__hip_bfloat16*)(smem + X_OFF + uw * 13312);
  __hip_bfloat16* sAt = (__hip_bfloat16*)(smem + A_OFF + ut * 13312);
  __hip_bfloat16* sXt = (__hip_bfloat16*)(smem + X_OFF + ut * 13312);
  unsigned char* sSmW = smem + SMALL + uw * 4096;
  unsigned char* sSmT = smem + SMALL + ut * 4096;
  // small layout per user: idx 0 | uatt 768 | ulin 1280 | lp 1792 | att 2048 |
  //                        pooled 2304 | comb 2816 | h1 3328
  int*   sIdxT   = (int*)  (sSmT);
  float* sUattW  = (float*)(sSmW + 768);
  float* sUlinT  = (float*)(sSmT + 1280);
  float* sLPW    = (float*)(sSmW + 1792);
  float* sLPU    = (float*)(sSmW + 1792);   // same (wave view)
  float* sAttT   = (float*)(sSmT + 2048);
  float* sPooledT= (float*)(sSmT + 2304);
  float* sCombT  = (float*)(sSmT + 2816);
  float* sCombW  = (float*)(sSmW + 2816);
  float* sH1W    = (float*)(sSmW + 3328);
  // tail scratch over dead sW (last read B11->B12), 8 KB per user
  float* sPool2T = (float*)(smem + W_OFF + ut * 8192);          // 256 f
  float* sCombPT = (float*)(smem + W_OFF + ut * 8192 + 4096);   // 256 f

  // ---- per-lane att3 fragment (all 128 cols across nt) ----
  float att3r[8];
#pragma unroll
  for (int nt = 0; nt < 8; ++nt) att3r[nt] = att3_w[nt * 16 + (lane & 15)];

  // ---- preload indices + per-user precomputed vectors ----
  if (t256 < 192) {
    int c = t256 >> 6, l = t256 & 63;
    int v = 0;
    if (l < 50) {
      const int* p = (c == 0) ? item_idx : (c == 1) ? rat_idx : time_idx;
      v = p[(b * 2 + ut) * 50 + l];
    }
    sIdxT[t256] = v;
  }
  {
    const int uid = user_idx[b * 2 + ut];
    float* sUattT = (float*)(sSmT + 768);
    if (t256 < 128) sUattT[t256]       = Pu [(long)uid * 128 + t256];
    else            sUlinT[t256 - 128] = Pu2[(long)uid * 128 + (t256 - 128)];
  }
  __syncthreads();  // B0

  auto stage16 = [&](const __hip_bfloat16* __restrict__ src) {
#pragma unroll
    for (int i = 0; i < 2; ++i) {
      int g = tid + i * 512;                // 1024 x 16B = 16 KB
      __builtin_amdgcn_global_load_lds(
          (__attribute__((address_space(1))) void*)(void*)(src + g * 8),
          (__attribute__((address_space(3))) void*)(void*)(sW + g * 8), 16, 0, 0);
    }
  };

  f32x4 acc[8];
  const f32x4 zf = {0.f, 0.f, 0.f, 0.f};
  auto zacc = [&]() {
#pragma unroll
    for (int j = 0; j < 8; ++j) acc[j] = zf;
  };

  // ===== phase 0: stage ne1 h0; x1 = relu(Pi[item]+Pr'[rat]+Pt[time]) -> sA =====
  stage16(wprep + 3 * WCHUNK);
#pragma unroll
  for (int i = 0; i < 4; ++i) {
    int g = t256 + i * 256;
    if (g < 832) {                         // 52 rows x 16 kb-blocks of 8 elems
      int row = g >> 4, kb = g & 15;
      uint4 pk = {0u, 0u, 0u, 0u};
      if (row < 50) {
        const bf16x8 pv = *(const bf16x8*)(Pi + (long)sIdxT[row] * 128 + kb * 8);
        const float4* pr4 = (const float4*)(Pr + (long)sIdxT[64 + row] * 128) + kb * 2;
        const float4* pt4 = (const float4*)(Pt + (long)sIdxT[128 + row] * 128) + kb * 2;
        float4 r0 = pr4[0], r1 = pr4[1];
        float4 t0 = pt4[0], t1 = pt4[1];
        float s0 = fmaxf((float)pv[0] + r0.x + t0.x, 0.f);
        float s1 = fmaxf((float)pv[1] + r0.y + t0.y, 0.f);
        float s2 = fmaxf((float)pv[2] + r0.z + t0.z, 0.f);
        float s3 = fmaxf((float)pv[3] + r0.w + t0.w, 0.f);
        float s4 = fmaxf((float)pv[4] + r1.x + t1.x, 0.f);
        float s5 = fmaxf((float)pv[5] + r1.y + t1.y, 0.f);
        float s6 = fmaxf((float)pv[6] + r1.z + t1.z, 0.f);
        float s7 = fmaxf((float)pv[7] + r1.w + t1.w, 0.f);
        pk.x = ((unsigned)bf_bits(s1) << 16) | bf_bits(s0);
        pk.y = ((unsigned)bf_bits(s3) << 16) | bf_bits(s2);
        pk.z = ((unsigned)bf_bits(s5) << 16) | bf_bits(s4);
        pk.w = ((unsigned)bf_bits(s7) << 16) | bf_bits(s6);
      }
      *(uint4*)(sAt + row * 128 + ((kb ^ (row & 15)) << 3)) = pk;
    }
  }
  __syncthreads();  // B1

  // ===== ne1: x = relu(x1 @ ne1_w + b) =====
  zacc();
  mfma_half8(sAw, sW, acc, 0, m16, lane);
  __syncthreads();  // B2
  stage16(wprep + 3 * WCHUNK + WHALF);
  __syncthreads();  // B3
  mfma_half8(sAw, sW, acc, 1, m16, lane);
  __syncthreads();  // B4
  stage16(wprep + 4 * WCHUNK);
  epilogue8(acc, ne1_b, nullptr, sXw, m16, lane);  // x -> sX
  __syncthreads();  // B5

  // ===== att1: a1 = relu(x @ att1_w[:128] + Pu[u] + b) =====
  zacc();
  mfma_half8(sXw, sW, acc, 0, m16, lane);
  __syncthreads();  // B6
  stage16(wprep + 4 * WCHUNK + WHALF);
  __syncthreads();  // B7
  mfma_half8(sXw, sW, acc, 1, m16, lane);
  __syncthreads();  // B8
  stage16(wprep + 5 * WCHUNK);
  epilogue8(acc, att1_b, sUattW, sAw, m16, lane);  // a1 -> sA
  __syncthreads();  // B9

  // ===== att2 + in-register logits =====
  zacc();
  mfma_half8(sAw, sW, acc, 0, m16, lane);
  __syncthreads();  // B10
  stage16(wprep + 5 * WCHUNK + WHALF);
  __syncthreads();  // B11
  mfma_half8(sAw, sW, acc, 1, m16, lane);
  {
    float lp[4] = {0.f, 0.f, 0.f, 0.f};
#pragma unroll
    for (int nt = 0; nt < 8; ++nt) {
      const int col = nt * 16 + (lane & 15);
      const float b2 = att2_b[col];
#pragma unroll
      for (int r = 0; r < 4; ++r)
        lp[r] += fmaxf(acc[nt][r] + b2, 0.f) * att3r[nt];
    }
#pragma unroll
    for (int off = 1; off < 16; off <<= 1) {
#pragma unroll
      for (int r = 0; r < 4; ++r) lp[r] += __shfl_xor(lp[r], off);
    }
    if ((lane & 15) == 0) {
      const int rowb = m16 * 16 + ((lane >> 4) << 2);
#pragma unroll
      for (int r = 0; r < 4; ++r) sLPW[rowb + r] = lp[r];
    }
  }
  __syncthreads();  // B12  (sW dead until next kernel launch)

  // ===== softmax over 50 (one wave per user; att3_b cancels under softmax) =====
  if (m16 == 0) {           // waves 0 (user 0) and 4 (user 1)
    float v = (lane < 50) ? sLPU[lane] : -3.4e38f;
    float m = v;
    for (int off = 32; off > 0; off >>= 1) m = fmaxf(m, __shfl_xor(m, off));
    float e = (lane < 50) ? __expf(v - m) : 0.f;
    float s = e;
    for (int off = 32; off > 0; off >>= 1) s += __shfl_xor(s, off);
    float* sAttW = (float*)(sSmW + 2048);
    sAttW[lane] = e / s;
  }
  __syncthreads();  // B13

  // ===== pooled partials (2 per d), scratch over dead sW =====
  {
    int q = t256 >> 7, d = t256 & 127;
    const int cblk = d >> 3, clo = d & 7;
    float s = 0.f;
    for (int l = q; l < 50; l += 2)
      s += sAttT[l] * (float)sXt[l * 128 + ((cblk ^ (l & 15)) << 3) + clo];
    sPool2T[q * 128 + d] = s;
  }
  __syncthreads();  // B14
  if (t256 < 128)
    sPooledT[t256] = sPool2T[t256] + sPool2T[128 + t256];
  __syncthreads();  // B15

  // ===== comb = relu(Pu2[u] + pooled @ lin_w[128:] + lin_b), 2 k-partials =====
  {
    int q = t256 >> 7, d = t256 & 127;
    float s = 0.f;
    for (int j = q * 64; j < q * 64 + 64; ++j) s += sPooledT[j] * lin_w[(128 + j) * 128 + d];
    sCombPT[q * 128 + d] = s;
  }
  __syncthreads();  // B16
  if (t256 < 128)
    sCombT[t256] = fmaxf(sCombPT[t256] + sCombPT[128 + t256]
                         + sUlinT[t256] + lin_b[t256], 0.f);
  __syncthreads();  // B17

  // ===== head: one wave per user =====
  if (m16 == 0) {
    if (lane < 32) {
      float s = w1_b[lane];
      for (int k = 0; k < 128; ++k) s += sCombW[k] * w1_w[k * 32 + lane];
      s = (s - bn1_m[lane]) * rsqrtf(bn1_v[lane] + 1e-5f) * bn1_g[lane] + bn1_b[lane];
      sH1W[lane] = fmaxf(s, 0.f);
    }
    if (lane < 16) {
      float s = w2_b[lane];
      for (int k = 0; k < 32; ++k) s += sH1W[k] * w2_w[k * 16 + lane];
      s = (s - bn2_m[lane]) * rsqrtf(bn2_v[lane] + 1e-5f) * bn2_g[lane] + bn2_b[lane];
      float p = fmaxf(s, 0.f) * w3_w[lane];   // relu(h2) then dot w3
      p += __shfl_xor(p, 1); p += __shfl_xor(p, 2);
      p += __shfl_xor(p, 4); p += __shfl_xor(p, 8);
      if (lane == 0) out[b * 2 + uw] = p + w3_b[0];
    }
  }
}

extern "C" void kernel_launch(void* const* d_in, const int* in_sizes, int n_in,
                              void* d_out, int out_size, void* d_ws, size_t ws_size,
                              hipStream_t stream) {
  const float* u2e    = (const float*)d_in[0];
  const float* i2e    = (const float*)d_in[1];
  const float* r2e    = (const float*)d_in[2];
  const float* t2e    = (const float*)d_in[3];
  const float* ne_w   = (const float*)d_in[4];
  const float* ne_b   = (const float*)d_in[5];
  const float* ne1_w  = (const float*)d_in[6];
  const float* ne1_b  = (const float*)d_in[7];
  const float* att1_w = (const float*)d_in[8];
  const float* att1_b = (const float*)d_in[9];
  const float* att2_w = (const float*)d_in[10];
  const float* att2_b = (const float*)d_in[11];
  const float* att3_w = (const float*)d_in[12];
  const float* att3_b = (const float*)d_in[13];
  const float* lin_w  = (const float*)d_in[14];
  const float* lin_b  = (const float*)d_in[15];
  const float* w1_w   = (const float*)d_in[16];
  const float* w1_b   = (const float*)d_in[17];
  const float* bn1_g  = (const float*)d_in[18];
  const float* bn1_b  = (const float*)d_in[19];
  const float* bn1_m  = (const float*)d_in[20];
  const float* bn1_v  = (const float*)d_in[21];
  const float* w2_w   = (const float*)d_in[22];
  const float* w2_b   = (const float*)d_in[23];
  const float* bn2_g  = (const float*)d_in[24];
  const float* bn2_b  = (const float*)d_in[25];
  const float* bn2_m  = (const float*)d_in[26];
  const float* bn2_v  = (const float*)d_in[27];
  const float* w3_w   = (const float*)d_in[28];
  const float* w3_b   = (const float*)d_in[29];
  const int* user_idx = (const int*)d_in[30];
  const int* item_idx = (const int*)d_in[31];
  const int* rat_idx  = (const int*)d_in[32];
  const int* time_idx = (const int*)d_in[33];
  (void)att3_b;  // constant shift under softmax — cancels

  char* ws = (char*)d_ws;
  __hip_bfloat16* wprep = (__hip_bfloat16*)(ws + WS_WPREP);
  __hip_bfloat16* Pi = (__hip_bfloat16*)(ws + WS_PI);
  float* Pt  = (float*)(ws + WS_PT);
  float* Pr  = (float*)(ws + WS_PR);
  float* Pu  = (float*)(ws + WS_PU);
  float* Pu2 = (float*)(ws + WS_PU2);
  float* out = (float*)d_out;

  prep_weights_kernel<<<32, dim3(64, 4), 0, stream>>>(ne_w, ne1_w, att1_w, att2_w,
                                                      lin_w, wprep);
  pgemm_kernel<<<1894, 512, 0, stream>>>(i2e, r2e, t2e, u2e, ne_b, wprep,
                                         Pi, Pt, Pr, Pu, Pu2);
  graphdec_main<<<2048, 512, 0, stream>>>(
      Pi, Pt, Pr, Pu, Pu2, ne1_b, att1_b, att2_b, att3_w,
      lin_w, lin_b, w1_w, w1_b, bn1_g, bn1_b, bn1_m, bn1_v, w2_w, w2_b,
      bn2_g, bn2_b, bn2_m, bn2_v, w3_w, w3_b,
      user_idx, item_idx, rat_idx, time_idx, wprep, out);
}